// Round 17
// baseline (122.324 us; speedup 1.0000x reference)
//
#include <hip/hip_runtime.h>
#include <math.h>

#define NHEADS 4
#define HDIM   32
#define DMODEL 128
#define SLEN   8192
#define BATCH  8
#define QKVC   384   // 3 * NHEADS * HDIM

typedef __bf16 bf16x8 __attribute__((ext_vector_type(8)));
typedef float  f32x4  __attribute__((ext_vector_type(4)));

// round-to-nearest-even f32 -> bf16 bits
static __device__ __forceinline__ unsigned short f2bf(float f) {
    union { float f; unsigned int u; } v; v.f = f;
    unsigned int r = (v.u + 0x7FFFu + ((v.u >> 16) & 1u)) >> 16;
    return (unsigned short)r;
}
// hardware cvt pack (v_cvt_pk_bf16_f32)
static __device__ __forceinline__ unsigned int pk2(float a, float b) {
    unsigned short ua = __builtin_bit_cast(unsigned short, (__bf16)a);
    unsigned short ub = __builtin_bit_cast(unsigned short, (__bf16)b);
    return (unsigned int)ua | ((unsigned int)ub << 16);
}

// ---------------------------------------------------------------------------
// Kernel P: prep. blockIdx segments:
//   [0,64) : W_out f32[8192][128] -> Wt bf16 [128][8192] (transpose+cvt)
//   [64,88): W_qkv -> MFMA fragment buffer wfb (bf16, fragment order)
//            wfb[((J*4+ks)*64+lane)*8+e] = bf16(Wqkv[(ks*32+(lane>>4)*8+e)*384
//                                               + J*16 + (lane&15)])
// ---------------------------------------------------------------------------
__global__ __launch_bounds__(256) void k_prep(
    const float* __restrict__ Wout, unsigned short* __restrict__ Wt,
    const float* __restrict__ Wqkv, unsigned short* __restrict__ wfb)
{
    const int tid = threadIdx.x;
    const int bx  = blockIdx.x;

    if (bx < 64) {
        __shared__ unsigned short ts[128][136];
        const float* src = Wout + (long)bx * 128 * 128;
        #pragma unroll
        for (int i = 0; i < 64; ++i) {
            const int idx = tid + i * 256;
            const int kk = idx >> 7, n = idx & 127;
            ts[n][kk] = f2bf(src[idx]);
        }
        __syncthreads();
        #pragma unroll
        for (int i = 0; i < 64; ++i) {
            const int idx = tid + i * 256;
            const int n = idx >> 7, kk = idx & 127;
            Wt[(long)n * SLEN + bx * 128 + kk] = ts[n][kk];
        }
    } else {
        const int idx  = (bx - 64) * 256 + tid;   // 0..6143
        const int lane = idx & 63;
        const int ks   = (idx >> 6) & 3;
        const int J    = idx >> 8;                // 0..23 channel tile
        const int ch   = J * 16 + (lane & 15);
        const int kb   = ks * 32 + (lane >> 4) * 8;
        unsigned short t[8];
        #pragma unroll
        for (int e = 0; e < 8; ++e) t[e] = f2bf(Wqkv[(kb + e) * QKVC + ch]);
        *(uint4*)(wfb + (long)idx * 8) = *(const uint4*)t;
    }
}

// ---------------------------------------------------------------------------
// Kernel 1: wave-autonomous fused QKV + head-mixing attention.
// 256 blocks x 512 thr (8 waves); ONE barrier total (after W staged to LDS).
// Each wave independently processes 2 tiles of 16 positions:
//   MFMA with SWAPPED operands mfma(x_Afrag, W_Bfrag): D row = position,
//   col = channel -> acc[24] holds the wave's 16 positions x 384 channels,
//   position p's channels in the 16 lanes of one lhi-group.
//   Softmax: per-lane partials + shfl_xor(1,2,4,8) within the group. PV
//   lane-local. os staged in wave-private LDS (reuses x region), coalesced
//   store. No cross-wave exchange, no steady-state barriers.
// W fragments read from LDS (98 KB) -- not resident (R14 spill trap), not
// per-use L2 (R6 latency trap). acc[24]=96 VGPR (nt=1 avoids R9's 192).
// ---------------------------------------------------------------------------
__global__ __launch_bounds__(512, 1) void k_fused_wa(
    const float* __restrict__ x,
    const unsigned short* __restrict__ wfb,
    const float* __restrict__ bqkv,
    unsigned short* __restrict__ attn_out)   // bf16 [65536][128]
{
    __shared__ unsigned short wlds[6144 * 8];      // 98304 B, fragment order
    __shared__ unsigned short xos[8][16 * 136];    // per-wave x / os region
    __shared__ float blds[QKVC];

    const int tid  = threadIdx.x;
    const int lane = tid & 63;
    const int wave = tid >> 6;          // 0..7
    const int l16  = lane & 15;
    const int lhi  = lane >> 4;

    // ---- prologue: cooperative W stage + bias stage, ONE barrier ----
    #pragma unroll
    for (int i = 0; i < 12; ++i) {
        const int idx = tid + i * 512;  // 0..6143
        *(uint4*)(wlds + (long)idx * 8) = *(const uint4*)(wfb + (long)idx * 8);
    }
    if (tid < QKVC) blds[tid] = bqkv[tid];
    __syncthreads();

    unsigned short* myxs = &xos[wave][0];
    const int srow = lane >> 2;          // 0..15
    const int scol = (lane & 3) * 32;    // 0,32,64,96
    const long wbase = ((long)blockIdx.x * 8 + wave) * 32;

    // initial x prefetch (tile 0): 32 f32 per lane
    float4 xv[8];
    {
        const float* src = x + (wbase + srow) * DMODEL + scol;
        #pragma unroll
        for (int i = 0; i < 8; ++i) xv[i] = *(const float4*)(src + i * 4);
    }

    const float scale = 0.17677669529663687f;   // 32^-0.5

    for (int t = 0; t < 2; ++t) {
        const long pb = wbase + t * 16;

        // ---- stage x regs -> myxs (bf16), then build A-frags ----
        #pragma unroll
        for (int i = 0; i < 4; ++i) {
            unsigned int u[4] = {
                pk2(xv[2*i].x,   xv[2*i].y),   pk2(xv[2*i].z,   xv[2*i].w),
                pk2(xv[2*i+1].x, xv[2*i+1].y), pk2(xv[2*i+1].z, xv[2*i+1].w) };
            *(uint4*)(myxs + srow * 136 + scol + i * 8) = *(const uint4*)u;
        }
        bf16x8 af[4];
        #pragma unroll
        for (int ks = 0; ks < 4; ++ks)
            af[ks] = __builtin_bit_cast(bf16x8,
                *(const uint4*)(myxs + l16 * 136 + ks * 32 + lhi * 8));

        // prefetch next tile's x (covered by MFMA + softmax)
        if (t == 0) {
            const float* src = x + (pb + 16 + srow) * DMODEL + scol;
            #pragma unroll
            for (int i = 0; i < 8; ++i) xv[i] = *(const float4*)(src + i * 4);
        }

        // ---- MFMA: acc[24] = 16 positions x 384 channels ----
        f32x4 acc[24];
        #pragma unroll
        for (int j = 0; j < 24; ++j) acc[j] = (f32x4){0.f, 0.f, 0.f, 0.f};
        #pragma unroll
        for (int j = 0; j < 24; ++j) {
            #pragma unroll
            for (int ks = 0; ks < 4; ++ks) {
                const bf16x8 wf = __builtin_bit_cast(bf16x8,
                    *(const uint4*)(wlds + (long)((j * 4 + ks) * 64 + lane) * 8));
                acc[j] = __builtin_amdgcn_mfma_f32_16x16x32_bf16(af[ks], wf, acc[j], 0, 0, 0);
            }
        }
        // bias (channel = j*16 + l16, same for all 4 row-positions)
        #pragma unroll
        for (int j = 0; j < 24; ++j) {
            const float b = blds[j * 16 + l16];
            acc[j][0] += b; acc[j][1] += b; acc[j][2] += b; acc[j][3] += b;
        }

        // ---- per-qh streaming softmax + PV + os writes (wave-private) ----
        #pragma unroll
        for (int qh = 0; qh < 4; ++qh) {
            float s[4][4];   // [kh][r]
            #pragma unroll
            for (int kh = 0; kh < 4; ++kh) {
                #pragma unroll
                for (int r = 0; r < 4; ++r) {
                    float v = acc[qh * 6][r]     * acc[kh * 6 + 2][r]
                            + acc[qh * 6 + 1][r] * acc[kh * 6 + 3][r];
                    v += __shfl_xor(v, 1);
                    v += __shfl_xor(v, 2);
                    v += __shfl_xor(v, 4);
                    v += __shfl_xor(v, 8);
                    s[kh][r] = v * scale;
                }
            }
            #pragma unroll
            for (int r = 0; r < 4; ++r) {
                const float m = fmaxf(fmaxf(s[0][r], s[1][r]), fmaxf(s[2][r], s[3][r]));
                const float e0 = __expf(s[0][r] - m);
                const float e1 = __expf(s[1][r] - m);
                const float e2 = __expf(s[2][r] - m);
                const float e3 = __expf(s[3][r] - m);
                const float inv = 1.f / (e0 + e1 + e2 + e3);
                const float o0 = (e0 * acc[4][r]  + e1 * acc[10][r]
                                + e2 * acc[16][r] + e3 * acc[22][r]) * inv;
                const float o1 = (e0 * acc[5][r]  + e1 * acc[11][r]
                                + e2 * acc[17][r] + e3 * acc[23][r]) * inv;
                const int p = lhi * 4 + r;
                myxs[p * 136 + qh * 32 + l16]      = f2bf(o0);
                myxs[p * 136 + qh * 32 + 16 + l16] = f2bf(o1);
            }
        }

        // ---- coalesced store: 16 pos x 128 ch = 256 uint4, 4 per lane ----
        #pragma unroll
        for (int i = 0; i < 4; ++i) {
            const int idx = lane + i * 64;
            const int row = idx >> 4, c8 = idx & 15;
            *(uint4*)(attn_out + (pb + row) * DMODEL + c8 * 8) =
                *(const uint4*)(myxs + row * 136 + c8 * 8);
        }
    }
}

// ---------------------------------------------------------------------------
// Kernel 2: final GEMM partials via bf16 MFMA.
//   C(1024x128) = Aflat(1024x8192 bf16) @ W(8192x128)
// Grid: 32 M-tiles (32 rows) x 16 K-chunks = 512 blocks (2 blocks/CU).
// ---------------------------------------------------------------------------
__global__ __launch_bounds__(256, 2) void k_fgemm_mfma(
    const unsigned short* __restrict__ attnBf,   // [1024][8192] bf16 (flat view)
    const unsigned short* __restrict__ WtBf,     // [128][8192] bf16
    float* __restrict__ P)                       // [16][1024][128] f32 partials
{
    __shared__ unsigned short As[32][136];
    __shared__ unsigned short Ws[128][136];

    const int tid   = threadIdx.x;
    const int mtile = blockIdx.x >> 4;     // 0..31
    const int kc    = blockIdx.x & 15;     // 0..15
    const int lane  = tid & 63;
    const int wave  = tid >> 6;
    const int l16   = lane & 15;
    const int lhi   = lane >> 4;

    f32x4 acc[2][2];
    #pragma unroll
    for (int mf = 0; mf < 2; ++mf)
        #pragma unroll
        for (int nt = 0; nt < 2; ++nt) acc[mf][nt] = (f32x4){0.f, 0.f, 0.f, 0.f};

    for (int st = 0; st < 4; ++st) {
        const int k0 = kc * 512 + st * 128;
        __syncthreads();
        #pragma unroll
        for (int i = 0; i < 2; ++i) {
            const int c = tid + i * 256;
            const int m = c >> 4, k8 = c & 15;
            const uint4 v = *(const uint4*)(attnBf + (long)(mtile * 32 + m) * SLEN + k0 + k8 * 8);
            *(uint4*)(&As[m][k8 * 8]) = v;
        }
        #pragma unroll
        for (int i = 0; i < 8; ++i) {
            const int c = tid + i * 256;
            const int n = c >> 4, k8 = c & 15;
            const uint4 v = *(const uint4*)(WtBf + (long)n * SLEN + k0 + k8 * 8);
            *(uint4*)(&Ws[n][k8 * 8]) = v;
        }
        __syncthreads();

        #pragma unroll
        for (int ks = 0; ks < 4; ++ks) {
            const int kk = ks * 32 + lhi * 8;
            bf16x8 af[2], bfr[2];
            #pragma unroll
            for (int mf = 0; mf < 2; ++mf)
                af[mf] = __builtin_bit_cast(bf16x8, *(const uint4*)(&As[mf * 16 + l16][kk]));
            #pragma unroll
            for (int nt = 0; nt < 2; ++nt)
                bfr[nt] = __builtin_bit_cast(bf16x8, *(const uint4*)(&Ws[(wave * 2 + nt) * 16 + l16][kk]));
            #pragma unroll
            for (int mf = 0; mf < 2; ++mf)
                #pragma unroll
                for (int nt = 0; nt < 2; ++nt)
                    acc[mf][nt] = __builtin_amdgcn_mfma_f32_16x16x32_bf16(af[mf], bfr[nt], acc[mf][nt], 0, 0, 0);
        }
    }

    float* Pp = P + ((long)kc * 1024 + mtile * 32) * 128;
    #pragma unroll
    for (int mf = 0; mf < 2; ++mf) {
        #pragma unroll
        for (int nt = 0; nt < 2; ++nt) {
            const int n = (wave * 2 + nt) * 16 + l16;
            #pragma unroll
            for (int r = 0; r < 4; ++r) {
                const int m = mf * 16 + lhi * 4 + r;
                Pp[m * 128 + n] = acc[mf][nt][r];
            }
        }
    }
}

// ---------------------------------------------------------------------------
// Kernel 3: reduce 16 K-chunk partials + bias -> out (also clears poison).
// ---------------------------------------------------------------------------
__global__ __launch_bounds__(256) void k_reduce(
    const float* __restrict__ P, const float* __restrict__ bout,
    float* __restrict__ out)
{
    const int idx = blockIdx.x * 256 + threadIdx.x;
    float v = bout[idx & 127];
    #pragma unroll
    for (int kcc = 0; kcc < 16; ++kcc) v += P[(long)kcc * 131072 + idx];
    out[idx] = v;
}

// ---------------------------------------------------------------------------
extern "C" void kernel_launch(void* const* d_in, const int* in_sizes, int n_in,
                              void* d_out, int out_size, void* d_ws, size_t ws_size,
                              hipStream_t stream)
{
    const float* x    = (const float*)d_in[0];
    const float* Wqkv = (const float*)d_in[1];
    const float* bqkv = (const float*)d_in[2];
    const float* Wout = (const float*)d_in[3];
    const float* bout = (const float*)d_in[4];
    float* out = (float*)d_out;

    // ws: [0,16M) attn bf16 | [16,18M) Wt bf16 | [18,26M) P f32 | [26M..) wfb
    unsigned short* attnBf = (unsigned short*)d_ws;
    unsigned short* WtBf   = (unsigned short*)((char*)d_ws + (16u << 20));
    float*          P      = (float*)((char*)d_ws + (18u << 20));
    unsigned short* wfb    = (unsigned short*)((char*)d_ws + (26u << 20));

    k_prep<<<88, 256, 0, stream>>>(Wout, WtBf, Wqkv, wfb);
    k_fused_wa<<<256, 512, 0, stream>>>(x, wfb, bqkv, attnBf);
    k_fgemm_mfma<<<512, 256, 0, stream>>>(attnBf, WtBf, P);
    k_reduce<<<512, 256, 0, stream>>>(P, bout, out);
}